// Round 2
// baseline (1499.943 us; speedup 1.0000x reference)
//
#include <hip/hip_runtime.h>
#include <hip/hip_bf16.h>

typedef short bf16x8 __attribute__((ext_vector_type(8)));
typedef float f32x4 __attribute__((ext_vector_type(4)));
typedef unsigned short u16;

__device__ __forceinline__ u16 f2bf(float v) {
    union { __hip_bfloat16 h; u16 u; } cv;
    cv.h = __float2bfloat16(v);
    return cv.u;
}

// ---------------- prep kernels ----------------
__global__ void prep_w1(const float* __restrict__ w, u16* __restrict__ o) {
    int idx = blockIdx.x * 256 + threadIdx.x;
    if (idx >= 25 * 512 * 512) return;
    int ic = idx & 511, rest = idx >> 9;
    int oc = rest & 511, tap = rest >> 9;
    int kh = tap / 5, kw = tap % 5;
    float v = w[(((size_t)oc * 512 + ic) * 5 + kh) * 5 + kw];
    o[idx] = f2bf(v);
}

__global__ void prep_w2(const float* __restrict__ w, u16* __restrict__ o) {
    int idx = blockIdx.x * 256 + threadIdx.x;
    if (idx >= 15 * 512 * 512) return;
    int ic = idx & 511, rest = idx >> 9;
    int oc = rest & 511, tap = rest >> 9;
    int kh = tap / 3, kw = tap % 3;
    float v = w[(((size_t)oc * 512 + ic) * 5 + kh) * 3 + kw];
    o[idx] = f2bf(v);
}

__global__ void prep_bn(const float* __restrict__ g, const float* __restrict__ b,
                        const float* __restrict__ m, const float* __restrict__ v,
                        float* __restrict__ scale, float* __restrict__ shift) {
    int i = blockIdx.x * 256 + threadIdx.x;
    if (i >= 512) return;
    float s = g[i] * rsqrtf(v[i] + 1e-5f);
    scale[i] = s;
    shift[i] = b[i] - m[i] * s;
}

// zero the H-pad rows {0,1,1026,1027} of gathered [8][1028][12][512] bf16
__global__ void zero_gpads(u16* __restrict__ g) {
    int idx = blockIdx.x * 256 + threadIdx.x;   // int4 units
    if (idx >= 8 * 4 * 768) return;             // 768 int4 per (b,row)
    int part = idx % 768;
    int combo = idx / 768;
    int b = combo >> 2, r4 = combo & 3;
    int row = (r4 < 2) ? r4 : (1024 + r4);      // 0,1,1026,1027
    u16* p = g + ((size_t)(b * 1028 + row) * 12 * 512) + (size_t)part * 8;
    *(int4*)p = int4{0, 0, 0, 0};
}

// ---------------- scores + top-k + gather ----------------
__global__ __launch_bounds__(256) void gather_topk(const float* __restrict__ x,
                                                   u16* __restrict__ g) {
    int bt = blockIdx.x;
    int b = bt >> 10, t = bt & 1023;
    const float* xb = x + (size_t)b * 1024 * 512;
    const float* xt = xb + (size_t)t * 512;
    __shared__ float xts[512];
    __shared__ float sc[23];
    __shared__ int sel[12];
    int tid = threadIdx.x;
    for (int i = tid; i < 512; i += 256) xts[i] = xt[i];
    __syncthreads();
    int j0 = t - 11; if (j0 < 0) j0 = 0;
    int j1 = t + 11; if (j1 > 1023) j1 = 1023;
    int C = j1 - j0 + 1;                        // 12..23, always >= 12
    int wave = tid >> 6, lane = tid & 63;
    for (int c = wave; c < C; c += 4) {
        const float* xj = xb + (size_t)(j0 + c) * 512;
        double s = 0.0;
        #pragma unroll
        for (int e = 0; e < 8; ++e) {
            int d = lane * 8 + e;
            s += (double)xj[d] * (double)xts[d];
        }
        #pragma unroll
        for (int off = 32; off; off >>= 1) s += __shfl_xor(s, off, 64);
        if (lane == 0) sc[c] = (float)(s / 22.627416997969522);  // / sqrt(512)
    }
    __syncthreads();
    if (tid == 0) {
        int cnt = 0;
        for (int c = 0; c < C; ++c) {
            float v = sc[c];
            int r = 0;
            for (int k = 0; k < C; ++k) {
                float u = sc[k];
                r += (u > v) || (u == v && k < c);   // stable: lower index wins ties
            }
            if (r < 12) sel[cnt++] = j0 + c;         // ascending j == sorted ids
        }
    }
    __syncthreads();
    u16* dst = g + ((size_t)(b * 1028 + t + 2) * 12) * 512;
    for (int i = tid; i < 12 * 512; i += 256) {
        int s_ = i >> 9, d = i & 511;
        dst[i] = f2bf(xb[(size_t)sel[s_] * 512 + d]);
    }
}

// ---------------- implicit-GEMM conv + bias + BN + ReLU ----------------
// A: [b][outH+KH-1][IN_W][512] bf16 (H zero-padded by 2 each side)
// Wb: [KH*KW][oc 512][ic 512] bf16
// out: OCMAJOR ? fp32 [b][512][outH][OW] : bf16 [b][outH][OW][512]
//
// Block tile: M = TH*OW positions x NT oc. 8 waves as 2(m) x 4(n),
// wave tile (M/2) x (NT/4), 16x16x32 bf16 MFMA.
// Ws double-buffered in LDS (ping-pong) + double-buffered weight regs:
// ONE barrier per tap; weight global loads for tap+2 issued during tap's
// MFMA phase (latency hidden under compute).

#define CSTEP(P, tapv, DOW) do {                                              \
    const int tap_ = (tapv);                                                  \
    const int kh_ = tap_ / KW;                                                \
    const int toff_ = kh_ * IN_W + (tap_ - kh_ * KW);                         \
    _Pragma("unroll")                                                         \
    for (int ks = 0; ks < 2; ++ks) {                                          \
      bf16x8 afr[MF], bfr[NF];                                                \
      _Pragma("unroll")                                                       \
      for (int mf = 0; mf < MF; ++mf)                                         \
        afr[mf] = *(const bf16x8*)&As[apos[mf] + toff_][ks * 32 + grp * 8];   \
      _Pragma("unroll")                                                       \
      for (int nf = 0; nf < NF; ++nf)                                         \
        bfr[nf] = *(const bf16x8*)&Ws[P][bocl[nf]][ks * 32 + grp * 8];        \
      _Pragma("unroll")                                                       \
      for (int mf = 0; mf < MF; ++mf)                                         \
        _Pragma("unroll")                                                     \
        for (int nf = 0; nf < NF; ++nf)                                       \
          acc[mf][nf] = __builtin_amdgcn_mfma_f32_16x16x32_bf16(              \
              afr[mf], bfr[nf], acc[mf][nf], 0, 0, 0);                        \
    }                                                                         \
    if (DOW) {                                                                \
      _Pragma("unroll")                                                       \
      for (int c4 = 0; c4 < NF; ++c4)                                         \
        *(int4*)&Ws[P ^ 1][ocl_t + c4 * 64][p8] = (P ? wra : wrb)[c4];        \
      if (tap_ + 2 < TAPS) {                                                  \
        _Pragma("unroll")                                                     \
        for (int c4 = 0; c4 < NF; ++c4)                                       \
          (P ? wrb : wra)[c4] = *(const int4*)(wthr +                         \
              (size_t)(tap_ + 2) * 262144 + (size_t)c4 * 32768 + ic0);        \
      }                                                                       \
      __syncthreads();                                                        \
    }                                                                         \
  } while (0)

template <int IN_W, int LOG_OW, int KH, int KW, int TH, int HTB, int NT, bool OCMAJOR>
__global__ __launch_bounds__(512, 2) void conv_bn_relu(
    const u16* __restrict__ A, const u16* __restrict__ Wb,
    const float* __restrict__ bias, const float* __restrict__ bnsc,
    const float* __restrict__ bnsh, void* __restrict__ outp) {
    constexpr int OW = 1 << LOG_OW;
    constexpr int M = TH * OW;
    constexpr int MF = M / 32;              // A-frags per wave (2 waves in m)
    constexpr int NF = NT / 64;             // B-frags per wave (4 waves in n)
    constexpr int HALO = TH + KH - 1;
    constexpr int AROWS = HALO * IN_W;
    constexpr int KP = 72;
    constexpr int OUTH = TH * HTB;
    constexpr int TAPS = KH * KW;
    constexpr int NTILES = 512 / NT;
    __shared__ u16 As[AROWS][KP];
    __shared__ u16 Ws[2][NT][KP];

    const int tid = threadIdx.x;
    const int bid = blockIdx.x;
    const int n0 = (bid % NTILES) * NT;
    const int mt = bid / NTILES;
    const int b = mt / HTB;
    const int h0 = (mt % HTB) * TH;

    const int lane = tid & 63;
    const int wv = tid >> 6;
    const int wm = wv >> 2, wn = wv & 3;
    const int l15 = lane & 15, grp = lane >> 4;

    int apos[MF];
    #pragma unroll
    for (int mf = 0; mf < MF; ++mf) {
        int pos = wm * MF * 16 + mf * 16 + l15;
        apos[mf] = (pos >> LOG_OW) * IN_W + (pos & (OW - 1));
    }
    int bocl[NF];
    #pragma unroll
    for (int nf = 0; nf < NF; ++nf) bocl[nf] = wn * (NT / 4) + nf * 16 + l15;

    // per-thread weight staging addresses: each thread covers NF int4
    const int ocl_t = tid >> 3;             // 0..63
    const int p8 = (tid & 7) * 8;           // short offset within row
    const u16* wthr = Wb + (size_t)(n0 + ocl_t) * 512 + p8;

    f32x4 acc[MF][NF];
    #pragma unroll
    for (int i = 0; i < MF; ++i)
        #pragma unroll
        for (int j = 0; j < NF; ++j) acc[i][j] = f32x4{0.f, 0.f, 0.f, 0.f};

    const size_t abase = ((size_t)b * (OUTH + KH - 1) + h0) * IN_W * 512;

    int4 wra[NF], wrb[NF];

    #pragma unroll 1
    for (int ic0 = 0; ic0 < 512; ic0 += 64) {
        if (ic0) __syncthreads();           // all waves done reading As/Ws[0]
        // issue wra <- (ic0, tap 0)
        #pragma unroll
        for (int c4 = 0; c4 < NF; ++c4)
            wra[c4] = *(const int4*)(wthr + (size_t)c4 * 32768 + ic0);
        // stage As(ic0)
        constexpr int CHA = AROWS * 8;
        #pragma unroll 1
        for (int c = tid; c < CHA; c += 512) {
            int rowIdx = c >> 3, part = c & 7;
            const int4 v = *(const int4*)(A + abase + (size_t)rowIdx * 512
                                          + ic0 + part * 8);
            *(int4*)&As[rowIdx][part * 8] = v;
        }
        // W(0): Ws[0] <- wra; issue wrb <- (ic0, tap 1)
        #pragma unroll
        for (int c4 = 0; c4 < NF; ++c4)
            *(int4*)&Ws[0][ocl_t + c4 * 64][p8] = wra[c4];
        #pragma unroll
        for (int c4 = 0; c4 < NF; ++c4)
            wrb[c4] = *(const int4*)(wthr + (size_t)262144 + (size_t)c4 * 32768 + ic0);
        __syncthreads();

        #pragma unroll 1
        for (int t = 0; t < TAPS - 1; t += 2) {
            CSTEP(0, t, true);
            CSTEP(1, t + 1, true);
        }
        CSTEP(0, TAPS - 1, false);          // TAPS odd -> last tap parity 0
    }

    // epilogue: y = relu(conv*sc + (bias*sc + sh))
    #pragma unroll
    for (int nf = 0; nf < NF; ++nf) {
        int oc = n0 + wn * (NT / 4) + nf * 16 + l15;
        float scv = bnsc[oc], shv = bnsh[oc], bi = bias[oc];
        float shh = fmaf(bi, scv, shv);
        #pragma unroll
        for (int mf = 0; mf < MF; ++mf) {
            #pragma unroll
            for (int r = 0; r < 4; ++r) {
                int pos = wm * MF * 16 + mf * 16 + grp * 4 + r;  // row=(lane>>4)*4+reg
                int lh = pos >> LOG_OW, lw = pos & (OW - 1);
                int h = h0 + lh;
                float v = fmaxf(fmaf(acc[mf][nf][r], scv, shh), 0.f);
                if (OCMAJOR) {
                    float* o = (float*)outp;
                    o[(((size_t)b * 512 + oc) * OUTH + h) * OW + lw] = v;
                } else {
                    u16* o = (u16*)outp;
                    o[(((size_t)b * OUTH + h) * OW + lw) * 512 + oc] = f2bf(v);
                }
            }
        }
    }
}

// ---------------- pools ----------------
// in: [8][1024][8][512] bf16 (relu'd, >=0) -> out: [8][516][4][512] bf16, pads zeroed
__global__ void pool1(const u16* __restrict__ in, u16* __restrict__ out) {
    int idx = blockIdx.x * 256 + threadIdx.x;
    if (idx >= 8 * 516 * 4 * 64) return;
    int icv = idx & 63, rest = idx >> 6;
    int w = rest & 3; rest >>= 2;
    int hp = rest % 516, b = rest / 516;
    u16* op = out + (((size_t)(b * 516 + hp) * 4 + w) * 512 + icv * 8);
    if (hp < 2 || hp >= 514) { *(int4*)op = int4{0, 0, 0, 0}; return; }
    int h = (hp - 2) * 2, wi = w * 2;
    const u16* p0 = in + (((size_t)(b * 1024 + h) * 8 + wi) * 512 + icv * 8);
    const u16* a = p0;
    const u16* bq = p0 + 512;
    const u16* c = p0 + 8 * 512;
    const u16* d = p0 + 8 * 512 + 512;
    u16 r[8];
    #pragma unroll
    for (int e = 0; e < 8; ++e) {
        u16 m1 = a[e] > bq[e] ? a[e] : bq[e];     // bf16 >=0: bit pattern monotone
        u16 m2 = c[e] > d[e] ? c[e] : d[e];
        r[e] = m1 > m2 ? m1 : m2;
    }
    *(int4*)op = *(const int4*)r;
}

// in: fp32 [8][512][512][2] (>=0) -> d_out fp32 [8][512][256]
__global__ void pool2(const float* __restrict__ in, float* __restrict__ out) {
    int idx = blockIdx.x * 256 + threadIdx.x;
    if (idx >= 8 * 512 * 256) return;
    const float* p = in + (size_t)idx * 4;
    out[idx] = fmaxf(fmaxf(p[0], p[1]), fmaxf(p[2], p[3]));
}

// ---------------- launch ----------------
extern "C" void kernel_launch(void* const* d_in, const int* in_sizes, int n_in,
                              void* d_out, int out_size, void* d_ws, size_t ws_size,
                              hipStream_t stream) {
    const float* x  = (const float*)d_in[0];
    const float* w1 = (const float*)d_in[1];
    const float* b1 = (const float*)d_in[2];
    const float* g1 = (const float*)d_in[3];
    const float* be1 = (const float*)d_in[4];
    const float* m1 = (const float*)d_in[5];
    const float* v1 = (const float*)d_in[6];
    const float* w2 = (const float*)d_in[7];
    const float* b2 = (const float*)d_in[8];
    const float* g2 = (const float*)d_in[9];
    const float* be2 = (const float*)d_in[10];
    const float* m2 = (const float*)d_in[11];
    const float* v2 = (const float*)d_in[12];
    float* out = (float*)d_out;

    char* ws = (char*)d_ws;
    u16* gathered  = (u16*)(ws);                   // 101,056,512 B
    u16* w1b       = (u16*)(ws + 101056512);       // 13,107,200 B
    u16* w2b       = (u16*)(ws + 114163712);       //  7,864,320 B
    float* bn1s    = (float*)(ws + 122028032);
    float* bn1t    = bn1s + 512;
    float* bn2s    = bn1s + 1024;
    float* bn2t    = bn1s + 1536;
    u16* conv1out  = (u16*)(ws + 122036224);       // 67,108,864 B
    u16* pooled1   = (u16*)(ws);                   // aliases gathered (dead by then)
    float* conv2out = (float*)(ws + 16908288);     // 16,777,216 B (inside gathered region)

    prep_w1<<<(25 * 512 * 512 + 255) / 256, 256, 0, stream>>>(w1, w1b);
    prep_w2<<<(15 * 512 * 512 + 255) / 256, 256, 0, stream>>>(w2, w2b);
    prep_bn<<<2, 256, 0, stream>>>(g1, be1, m1, v1, bn1s, bn1t);
    prep_bn<<<2, 256, 0, stream>>>(g2, be2, m2, v2, bn2s, bn2t);
    zero_gpads<<<(8 * 4 * 768 + 255) / 256, 256, 0, stream>>>(gathered);
    gather_topk<<<8192, 256, 0, stream>>>(x, gathered);

    // conv1: 256x256 tile, TH=32 (32 htiles/b), 2 n-tiles -> grid 8*32*2 = 512
    conv_bn_relu<12, 3, 5, 5, 32, 32, 256, false><<<512, 512, 0, stream>>>(
        gathered, w1b, b1, bn1s, bn1t, conv1out);
    pool1<<<(8 * 516 * 4 * 64 + 255) / 256, 256, 0, stream>>>(conv1out, pooled1);
    // conv2: 128x128 tile, TH=64 (8 htiles/b), 4 n-tiles -> grid 8*8*4 = 256
    conv_bn_relu<4, 1, 5, 3, 64, 8, 128, true><<<256, 512, 0, stream>>>(
        pooled1, w2b, b2, bn2s, bn2t, conv2out);
    pool2<<<(8 * 512 * 256 + 255) / 256, 256, 0, stream>>>(conv2out, out);
}

// Round 3
// 1359.342 us; speedup vs baseline: 1.1034x; 1.1034x over previous
//
#include <hip/hip_runtime.h>
#include <hip/hip_bf16.h>

typedef short bf16x8 __attribute__((ext_vector_type(8)));
typedef float f32x4 __attribute__((ext_vector_type(4)));
typedef unsigned short u16;

__device__ __forceinline__ u16 f2bf(float v) {
    union { __hip_bfloat16 h; u16 u; } cv;
    cv.h = __float2bfloat16(v);
    return cv.u;
}

__device__ __forceinline__ void gld_lds16(const u16* g, u16* l) {
    __builtin_amdgcn_global_load_lds(
        (const __attribute__((address_space(1))) void*)g,
        (__attribute__((address_space(3))) void*)l, 16, 0, 0);
}

// ---------------- prep kernels ----------------
__global__ void prep_w1(const float* __restrict__ w, u16* __restrict__ o) {
    int idx = blockIdx.x * 256 + threadIdx.x;
    if (idx >= 25 * 512 * 512) return;
    int ic = idx & 511, rest = idx >> 9;
    int oc = rest & 511, tap = rest >> 9;
    int kh = tap / 5, kw = tap % 5;
    float v = w[(((size_t)oc * 512 + ic) * 5 + kh) * 5 + kw];
    o[idx] = f2bf(v);
}

__global__ void prep_w2(const float* __restrict__ w, u16* __restrict__ o) {
    int idx = blockIdx.x * 256 + threadIdx.x;
    if (idx >= 15 * 512 * 512) return;
    int ic = idx & 511, rest = idx >> 9;
    int oc = rest & 511, tap = rest >> 9;
    int kh = tap / 3, kw = tap % 3;
    float v = w[(((size_t)oc * 512 + ic) * 5 + kh) * 3 + kw];
    o[idx] = f2bf(v);
}

__global__ void prep_bn(const float* __restrict__ g, const float* __restrict__ b,
                        const float* __restrict__ m, const float* __restrict__ v,
                        float* __restrict__ scale, float* __restrict__ shift) {
    int i = blockIdx.x * 256 + threadIdx.x;
    if (i >= 512) return;
    float s = g[i] * rsqrtf(v[i] + 1e-5f);
    scale[i] = s;
    shift[i] = b[i] - m[i] * s;
}

// zero the H-pad rows {0,1,1026,1027} of gathered [8][1028][12][512] bf16
__global__ void zero_gpads(u16* __restrict__ g) {
    int idx = blockIdx.x * 256 + threadIdx.x;   // int4 units
    if (idx >= 8 * 4 * 768) return;             // 768 int4 per (b,row)
    int part = idx % 768;
    int combo = idx / 768;
    int b = combo >> 2, r4 = combo & 3;
    int row = (r4 < 2) ? r4 : (1024 + r4);      // 0,1,1026,1027
    u16* p = g + ((size_t)(b * 1028 + row) * 12 * 512) + (size_t)part * 8;
    *(int4*)p = int4{0, 0, 0, 0};
}

// ---------------- scores + top-k + gather ----------------
__global__ __launch_bounds__(256) void gather_topk(const float* __restrict__ x,
                                                   u16* __restrict__ g) {
    int bt = blockIdx.x;
    int b = bt >> 10, t = bt & 1023;
    const float* xb = x + (size_t)b * 1024 * 512;
    const float* xt = xb + (size_t)t * 512;
    __shared__ float xts[512];
    __shared__ float sc[23];
    __shared__ int sel[12];
    int tid = threadIdx.x;
    for (int i = tid; i < 512; i += 256) xts[i] = xt[i];
    __syncthreads();
    int j0 = t - 11; if (j0 < 0) j0 = 0;
    int j1 = t + 11; if (j1 > 1023) j1 = 1023;
    int C = j1 - j0 + 1;                        // 12..23, always >= 12
    int wave = tid >> 6, lane = tid & 63;
    for (int c = wave; c < C; c += 4) {
        const float* xj = xb + (size_t)(j0 + c) * 512;
        double s = 0.0;
        #pragma unroll
        for (int e = 0; e < 8; ++e) {
            int d = lane * 8 + e;
            s += (double)xj[d] * (double)xts[d];
        }
        #pragma unroll
        for (int off = 32; off; off >>= 1) s += __shfl_xor(s, off, 64);
        if (lane == 0) sc[c] = (float)(s / 22.627416997969522);  // / sqrt(512)
    }
    __syncthreads();
    if (tid == 0) {
        int cnt = 0;
        for (int c = 0; c < C; ++c) {
            float v = sc[c];
            int r = 0;
            for (int k = 0; k < C; ++k) {
                float u = sc[k];
                r += (u > v) || (u == v && k < c);   // stable: lower index wins ties
            }
            if (r < 12) sel[cnt++] = j0 + c;         // ascending j == sorted ids
        }
    }
    __syncthreads();
    u16* dst = g + ((size_t)(b * 1028 + t + 2) * 12) * 512;
    for (int i = tid; i < 12 * 512; i += 256) {
        int s_ = i >> 9, d = i & 511;
        dst[i] = f2bf(xb[(size_t)sel[s_] * 512 + d]);
    }
}

// ---------------- implicit-GEMM conv + bias + BN + ReLU ----------------
// A: [b][outH+KH-1][IN_W][512] bf16 (H zero-padded). Wb: [tap][oc 512][ic 512].
// LDS layouts (swizzled, 128B rows of 8 16B-chunks):
//   As_l[row][chunk]  at row*64 + ((chunk ^ (row&7))<<3)   (holds 64-ic slab)
//   Ws_l[p][oc][chunk] at oc*64 + ((chunk ^ (oc&7))<<3)
// As staged via global_load_lds (linear LDS dest, pre-swizzled global src).
// Ws ping-pong: 1 barrier/tap, weight regs prefetched 2 taps ahead.
// 8 waves = 2(m) x 4(n); wave tile (MF*16) x (NT/4); 16x16x32 bf16 MFMA.

#define LOADW(DST, TN) do {                                                   \
    if ((TN) < TT) {                                                          \
        int icv2_ = (TN) / TAPS, tp2_ = (TN) - icv2_ * TAPS;                  \
        const u16* wp_ = wthr + (size_t)tp2_ * 262144 + icv2_ * 64;           \
        _Pragma("unroll")                                                     \
        for (int c4 = 0; c4 < NF; ++c4)                                       \
            DST[c4] = *(const int4*)(wp_ + (size_t)c4 * 32768);               \
    } } while (0)

#define STAGEA(IC0) do {                                                      \
    const u16* ga_ = gA + (IC0);                                              \
    _Pragma("unroll 1")                                                       \
    for (int c_ = wv; c_ < NCALL; c_ += 8)                                    \
        gld_lds16(ga_ + c_ * 4096 + aoff, &As_l[c_ * 512]);                   \
  } while (0)

#define BODY(T_, WSR, WSW, WLD, WST) do {                                     \
    int icv_ = (T_) / TAPS, tap_ = (T_) - icv_ * TAPS;                        \
    int kh_ = tap_ / KW, toff_ = kh_ * IN_W + (tap_ - kh_ * KW);              \
    LOADW(WLD, (T_) + 2);                                                     \
    if ((T_) + 1 < TT) {                                                      \
        _Pragma("unroll")                                                     \
        for (int c4 = 0; c4 < NF; ++c4)                                       \
            *(int4*)&WSW[wswb + c4 * 4096] = WST[c4];                         \
    }                                                                         \
    _Pragma("unroll")                                                         \
    for (int ks = 0; ks < 2; ++ks) {                                          \
        bf16x8 afr[MF], bfr[NF];                                              \
        _Pragma("unroll")                                                     \
        for (int mf = 0; mf < MF; ++mf) {                                     \
            int row_ = rowb[mf] + toff_;                                      \
            afr[mf] = *(const bf16x8*)&As_l[row_ * 64 +                       \
                          (((ks * 4 + grp) ^ (row_ & 7)) << 3)];              \
        }                                                                     \
        _Pragma("unroll")                                                     \
        for (int nf = 0; nf < NF; ++nf)                                       \
            bfr[nf] = *(const bf16x8*)&WSR[ocr[nf] * 64 +                     \
                          (((ks * 4 + grp) ^ (ocr[nf] & 7)) << 3)];           \
        _Pragma("unroll")                                                     \
        for (int mf = 0; mf < MF; ++mf)                                       \
            _Pragma("unroll")                                                 \
            for (int nf = 0; nf < NF; ++nf)                                   \
                acc[mf][nf] = __builtin_amdgcn_mfma_f32_16x16x32_bf16(        \
                    afr[mf], bfr[nf], acc[mf][nf], 0, 0, 0);                  \
    }                                                                         \
    if (tap_ == TAPS - 1 && (T_) != TT - 1) {                                 \
        __syncthreads();                                                      \
        STAGEA((icv_ + 1) * 64);                                              \
        __syncthreads();                                                      \
    } else if ((T_) != TT - 1) {                                              \
        __syncthreads();                                                      \
    }                                                                         \
  } while (0)

template <int IN_W, int LOG_OW, int KH, int KW, int TH, int HTB, int NT, int MF,
          bool OCMAJOR>
__global__ __launch_bounds__(512, 1) void conv_bn_relu(
    const u16* __restrict__ A, const u16* __restrict__ Wb,
    const float* __restrict__ bias, const float* __restrict__ bnsc,
    const float* __restrict__ bnsh, void* __restrict__ outp) {
    constexpr int OW = 1 << LOG_OW;
    constexpr int NF = NT / 64;
    constexpr int AROWS = (TH + KH - 1) * IN_W;
    constexpr int NCALL = AROWS / 8;
    constexpr int TAPS = KH * KW;
    constexpr int TT = 8 * TAPS;
    constexpr int OUTH = TH * HTB;
    constexpr int NTILES = 512 / NT;
    __shared__ u16 As_l[AROWS * 64];
    __shared__ u16 Ws_l[2][NT * 64];

    const int tid = threadIdx.x;
    const int bid = blockIdx.x;
    const int n0 = (bid % NTILES) * NT;
    const int mt = bid / NTILES;
    const int b = mt / HTB;
    const int h0 = (mt % HTB) * TH;

    const int lane = tid & 63;
    const int wv = tid >> 6;
    const int wm = wv >> 2, wn = wv & 3;
    const int l15 = lane & 15, grp = lane >> 4;

    int rowb[MF];
    #pragma unroll
    for (int mf = 0; mf < MF; ++mf) {
        int pos = wm * MF * 16 + mf * 16 + l15;
        rowb[mf] = (pos >> LOG_OW) * IN_W + (pos & (OW - 1));
    }
    int ocr[NF];
    #pragma unroll
    for (int nf = 0; nf < NF; ++nf) ocr[nf] = wn * (NT / 4) + nf * 16 + l15;

    // A-staging per-lane pre-swizzled global offset (shorts)
    const int aoff = (lane >> 3) * 512 + (((lane & 7) ^ ((lane >> 3) & 7)) * 8);
    // Ws staging: thread covers oc=(tid>>3)+c4*64, chunk=tid&7
    const int wswb = (tid >> 3) * 64 + ((((tid & 7) ^ ((tid >> 3) & 7))) << 3);
    const u16* wthr = Wb + (size_t)(n0 + (tid >> 3)) * 512 + (tid & 7) * 8;

    const size_t abase = ((size_t)b * (OUTH + KH - 1) + h0) * IN_W * 512;
    const u16* gA = A + abase;

    f32x4 acc[MF][NF];
    #pragma unroll
    for (int i = 0; i < MF; ++i)
        #pragma unroll
        for (int j = 0; j < NF; ++j) acc[i][j] = f32x4{0.f, 0.f, 0.f, 0.f};

    int4 wrE[NF], wrO[NF];

    // prologue: As(ic0=0) via DMA; Ws[0] <- W(0); wrO <- W(1)
    STAGEA(0);
    LOADW(wrE, 0);
    LOADW(wrO, 1);
    #pragma unroll
    for (int c4 = 0; c4 < NF; ++c4)
        *(int4*)&Ws_l[0][wswb + c4 * 4096] = wrE[c4];
    __syncthreads();   // drains gload_lds vmcnt + Ws[0] writes visible

    #pragma unroll 1
    for (int T = 0; T < TT; T += 2) {
        BODY(T,     Ws_l[0], Ws_l[1], wrE, wrO);
        BODY(T + 1, Ws_l[1], Ws_l[0], wrO, wrE);
    }

    // epilogue: y = relu(conv*sc + (bias*sc + sh))
    #pragma unroll
    for (int nf = 0; nf < NF; ++nf) {
        int oc = n0 + wn * (NT / 4) + nf * 16 + l15;
        float scv = bnsc[oc], shv = bnsh[oc], bi = bias[oc];
        float shh = fmaf(bi, scv, shv);
        #pragma unroll
        for (int mf = 0; mf < MF; ++mf) {
            #pragma unroll
            for (int r = 0; r < 4; ++r) {
                int pos = wm * MF * 16 + mf * 16 + grp * 4 + r;  // row=(lane>>4)*4+reg
                int lh = pos >> LOG_OW, lw = pos & (OW - 1);
                int h = h0 + lh;
                float v = fmaxf(fmaf(acc[mf][nf][r], scv, shh), 0.f);
                if (OCMAJOR) {
                    float* o = (float*)outp;
                    o[(((size_t)b * 512 + oc) * OUTH + h) * OW + lw] = v;
                } else {
                    u16* o = (u16*)outp;
                    o[(((size_t)b * OUTH + h) * OW + lw) * 512 + oc] = f2bf(v);
                }
            }
        }
    }
}

// ---------------- pools ----------------
// in: [8][1024][8][512] bf16 (relu'd, >=0) -> out: [8][516][4][512] bf16, pads zeroed
__global__ void pool1(const u16* __restrict__ in, u16* __restrict__ out) {
    int idx = blockIdx.x * 256 + threadIdx.x;
    if (idx >= 8 * 516 * 4 * 64) return;
    int icv = idx & 63, rest = idx >> 6;
    int w = rest & 3; rest >>= 2;
    int hp = rest % 516, b = rest / 516;
    u16* op = out + (((size_t)(b * 516 + hp) * 4 + w) * 512 + icv * 8);
    if (hp < 2 || hp >= 514) { *(int4*)op = int4{0, 0, 0, 0}; return; }
    int h = (hp - 2) * 2, wi = w * 2;
    const u16* p0 = in + (((size_t)(b * 1024 + h) * 8 + wi) * 512 + icv * 8);
    const u16* a = p0;
    const u16* bq = p0 + 512;
    const u16* c = p0 + 8 * 512;
    const u16* d = p0 + 8 * 512 + 512;
    u16 r[8];
    #pragma unroll
    for (int e = 0; e < 8; ++e) {
        u16 m1 = a[e] > bq[e] ? a[e] : bq[e];     // bf16 >=0: bit pattern monotone
        u16 m2 = c[e] > d[e] ? c[e] : d[e];
        r[e] = m1 > m2 ? m1 : m2;
    }
    *(int4*)op = *(const int4*)r;
}

// in: fp32 [8][512][512][2] (>=0) -> d_out fp32 [8][512][256]
__global__ void pool2(const float* __restrict__ in, float* __restrict__ out) {
    int idx = blockIdx.x * 256 + threadIdx.x;
    if (idx >= 8 * 512 * 256) return;
    const float* p = in + (size_t)idx * 4;
    out[idx] = fmaxf(fmaxf(p[0], p[1]), fmaxf(p[2], p[3]));
}

// ---------------- launch ----------------
extern "C" void kernel_launch(void* const* d_in, const int* in_sizes, int n_in,
                              void* d_out, int out_size, void* d_ws, size_t ws_size,
                              hipStream_t stream) {
    const float* x  = (const float*)d_in[0];
    const float* w1 = (const float*)d_in[1];
    const float* b1 = (const float*)d_in[2];
    const float* g1 = (const float*)d_in[3];
    const float* be1 = (const float*)d_in[4];
    const float* m1 = (const float*)d_in[5];
    const float* v1 = (const float*)d_in[6];
    const float* w2 = (const float*)d_in[7];
    const float* b2 = (const float*)d_in[8];
    const float* g2 = (const float*)d_in[9];
    const float* be2 = (const float*)d_in[10];
    const float* m2 = (const float*)d_in[11];
    const float* v2 = (const float*)d_in[12];
    float* out = (float*)d_out;

    char* ws = (char*)d_ws;
    u16* gathered  = (u16*)(ws);                   // 101,056,512 B
    u16* w1b       = (u16*)(ws + 101056512);       // 13,107,200 B
    u16* w2b       = (u16*)(ws + 114163712);       //  7,864,320 B
    float* bn1s    = (float*)(ws + 122028032);
    float* bn1t    = bn1s + 512;
    float* bn2s    = bn1s + 1024;
    float* bn2t    = bn1s + 1536;
    u16* conv1out  = (u16*)(ws + 122036224);       // 67,108,864 B
    u16* pooled1   = (u16*)(ws);                   // aliases gathered (dead by then)
    float* conv2out = (float*)(ws + 16908288);     // 16,777,216 B (inside gathered region)

    prep_w1<<<(25 * 512 * 512 + 255) / 256, 256, 0, stream>>>(w1, w1b);
    prep_w2<<<(15 * 512 * 512 + 255) / 256, 256, 0, stream>>>(w2, w2b);
    prep_bn<<<2, 256, 0, stream>>>(g1, be1, m1, v1, bn1s, bn1t);
    prep_bn<<<2, 256, 0, stream>>>(g2, be2, m2, v2, bn2s, bn2t);
    zero_gpads<<<(8 * 4 * 768 + 255) / 256, 256, 0, stream>>>(gathered);
    gather_topk<<<8192, 256, 0, stream>>>(x, gathered);

    // conv1: 256pos x 256oc tile, TH=32, grid 8*32*2 = 512
    conv_bn_relu<12, 3, 5, 5, 32, 32, 256, 8, false><<<512, 512, 0, stream>>>(
        gathered, w1b, b1, bn1s, bn1t, conv1out);
    pool1<<<(8 * 516 * 4 * 64 + 255) / 256, 256, 0, stream>>>(conv1out, pooled1);
    // conv2: 64pos x 256oc tile, TH=32, grid 8*16*2 = 256
    conv_bn_relu<4, 1, 5, 3, 32, 16, 256, 2, true><<<256, 512, 0, stream>>>(
        pooled1, w2b, b2, bn2s, bn2t, conv2out);
    pool2<<<(8 * 512 * 256 + 255) / 256, 256, 0, stream>>>(conv2out, out);
}

// Round 4
// 1179.960 us; speedup vs baseline: 1.2712x; 1.1520x over previous
//
#include <hip/hip_runtime.h>
#include <hip/hip_bf16.h>

typedef short bf16x8 __attribute__((ext_vector_type(8)));
typedef float f32x4 __attribute__((ext_vector_type(4)));
typedef unsigned short u16;

__device__ __forceinline__ u16 f2bf(float v) {
    union { __hip_bfloat16 h; u16 u; } cv;
    cv.h = __float2bfloat16(v);
    return cv.u;
}

__device__ __forceinline__ void gld_lds16(const u16* g, u16* l) {
    __builtin_amdgcn_global_load_lds(
        (const __attribute__((address_space(1))) void*)g,
        (__attribute__((address_space(3))) void*)l, 16, 0, 0);
}

// ---------------- prep kernels ----------------
__global__ void prep_w1(const float* __restrict__ w, u16* __restrict__ o) {
    int idx = blockIdx.x * 256 + threadIdx.x;
    if (idx >= 25 * 512 * 512) return;
    int ic = idx & 511, rest = idx >> 9;
    int oc = rest & 511, tap = rest >> 9;
    int kh = tap / 5, kw = tap % 5;
    float v = w[(((size_t)oc * 512 + ic) * 5 + kh) * 5 + kw];
    o[idx] = f2bf(v);
}

__global__ void prep_w2(const float* __restrict__ w, u16* __restrict__ o) {
    int idx = blockIdx.x * 256 + threadIdx.x;
    if (idx >= 15 * 512 * 512) return;
    int ic = idx & 511, rest = idx >> 9;
    int oc = rest & 511, tap = rest >> 9;
    int kh = tap / 3, kw = tap % 3;
    float v = w[(((size_t)oc * 512 + ic) * 5 + kh) * 3 + kw];
    o[idx] = f2bf(v);
}

__global__ void prep_bn(const float* __restrict__ g, const float* __restrict__ b,
                        const float* __restrict__ m, const float* __restrict__ v,
                        float* __restrict__ scale, float* __restrict__ shift) {
    int i = blockIdx.x * 256 + threadIdx.x;
    if (i >= 512) return;
    float s = g[i] * rsqrtf(v[i] + 1e-5f);
    scale[i] = s;
    shift[i] = b[i] - m[i] * s;
}

// zero the H-pad rows {0,1,1026,1027} of gathered [8][1028][12][512] bf16
__global__ void zero_gpads(u16* __restrict__ g) {
    int idx = blockIdx.x * 256 + threadIdx.x;   // int4 units
    if (idx >= 8 * 4 * 768) return;             // 768 int4 per (b,row)
    int part = idx % 768;
    int combo = idx / 768;
    int b = combo >> 2, r4 = combo & 3;
    int row = (r4 < 2) ? r4 : (1024 + r4);      // 0,1,1026,1027
    u16* p = g + ((size_t)(b * 1028 + row) * 12 * 512) + (size_t)part * 8;
    *(int4*)p = int4{0, 0, 0, 0};
}

// ---------------- scores + top-k + gather ----------------
__global__ __launch_bounds__(256) void gather_topk(const float* __restrict__ x,
                                                   u16* __restrict__ g) {
    int bt = blockIdx.x;
    int b = bt >> 10, t = bt & 1023;
    const float* xb = x + (size_t)b * 1024 * 512;
    const float* xt = xb + (size_t)t * 512;
    __shared__ float xts[512];
    __shared__ float sc[23];
    __shared__ int sel[12];
    int tid = threadIdx.x;
    for (int i = tid; i < 512; i += 256) xts[i] = xt[i];
    __syncthreads();
    int j0 = t - 11; if (j0 < 0) j0 = 0;
    int j1 = t + 11; if (j1 > 1023) j1 = 1023;
    int C = j1 - j0 + 1;                        // 12..23, always >= 12
    int wave = tid >> 6, lane = tid & 63;
    for (int c = wave; c < C; c += 4) {
        const float* xj = xb + (size_t)(j0 + c) * 512;
        double s = 0.0;
        #pragma unroll
        for (int e = 0; e < 8; ++e) {
            int d = lane * 8 + e;
            s += (double)xj[d] * (double)xts[d];
        }
        #pragma unroll
        for (int off = 32; off; off >>= 1) s += __shfl_xor(s, off, 64);
        if (lane == 0) sc[c] = (float)(s / 22.627416997969522);  // / sqrt(512)
    }
    __syncthreads();
    if (tid == 0) {
        int cnt = 0;
        for (int c = 0; c < C; ++c) {
            float v = sc[c];
            int r = 0;
            for (int k = 0; k < C; ++k) {
                float u = sc[k];
                r += (u > v) || (u == v && k < c);   // stable: lower index wins ties
            }
            if (r < 12) sel[cnt++] = j0 + c;         // ascending j == sorted ids
        }
    }
    __syncthreads();
    u16* dst = g + ((size_t)(b * 1028 + t + 2) * 12) * 512;
    for (int i = tid; i < 12 * 512; i += 256) {
        int s_ = i >> 9, d = i & 511;
        dst[i] = f2bf(xb[(size_t)sel[s_] * 512 + d]);
    }
}

// ---------------- implicit-GEMM conv + bias + BN + ReLU ----------------
// A: [b][outH+KH-1][IN_W][512] bf16 (H zero-padded). Wb: [tap][oc 512][ic 512].
// LDS layouts (content-swizzled, 128B rows of 8 16B-chunks):
//   slot (row, s) holds global chunk s ^ (row&7); read chunk c at s = c^(row&7).
// BOTH As and Ws staged via global_load_lds width=16 (linear LDS dest,
// pre-swizzled per-lane GLOBAL source). No VGPR round-trip, no ds_write.
// Ws ping-pong: 1 barrier/body; DMA for tap T+1 issued at start of body T,
// drained by the barrier's vmcnt(0). s_setprio(1) around MFMA cluster.
// 8 waves = 2(m) x 4(n); wave tile (MF*16) x (NT/4); 16x16x32 bf16 MFMA.

#define STAGEA(IC0) do {                                                      \
    const u16* ga_ = gA + (IC0);                                              \
    _Pragma("unroll 1")                                                       \
    for (int c_ = wv; c_ < NCALL; c_ += 8)                                    \
        gld_lds16(ga_ + c_ * 4096 + aoff, &As_l[c_ * 512]);                   \
  } while (0)

#define STAGEW(P, TN) do {                                                    \
    if ((TN) < TT) {                                                          \
        int icv2_ = (TN) / TAPS, tp2_ = (TN) - icv2_ * TAPS;                  \
        const u16* wp_ = Wb + (size_t)tp2_ * 262144 + (size_t)n0 * 512        \
                         + icv2_ * 64;                                        \
        _Pragma("unroll")                                                     \
        for (int i_ = 0; i_ < WCALL / 8; ++i_) {                              \
            int k_ = wv * (WCALL / 8) + i_;                                   \
            gld_lds16(wp_ + (size_t)k_ * 4096 + aoff, &Ws_l[(P)][k_ * 512]);  \
        }                                                                     \
    } } while (0)

#define BODY(T_, P_) do {                                                     \
    int icv_ = (T_) / TAPS, tap_ = (T_) - icv_ * TAPS;                        \
    int kh_ = tap_ / KW, toff_ = kh_ * IN_W + (tap_ - kh_ * KW);              \
    STAGEW((P_) ^ 1, (T_) + 1);                                               \
    __builtin_amdgcn_s_setprio(1);                                            \
    _Pragma("unroll")                                                         \
    for (int ks = 0; ks < 2; ++ks) {                                          \
        bf16x8 afr[MF], bfr[NF];                                              \
        _Pragma("unroll")                                                     \
        for (int mf = 0; mf < MF; ++mf) {                                     \
            int row_ = rowb[mf] + toff_;                                      \
            afr[mf] = *(const bf16x8*)&As_l[row_ * 64 +                       \
                          (((ks * 4 + grp) ^ (row_ & 7)) << 3)];              \
        }                                                                     \
        _Pragma("unroll")                                                     \
        for (int nf = 0; nf < NF; ++nf)                                       \
            bfr[nf] = *(const bf16x8*)&Ws_l[(P_)][ocr[nf] * 64 +              \
                          (((ks * 4 + grp) ^ (ocr[nf] & 7)) << 3)];           \
        _Pragma("unroll")                                                     \
        for (int mf = 0; mf < MF; ++mf)                                       \
            _Pragma("unroll")                                                 \
            for (int nf = 0; nf < NF; ++nf)                                   \
                acc[mf][nf] = __builtin_amdgcn_mfma_f32_16x16x32_bf16(        \
                    afr[mf], bfr[nf], acc[mf][nf], 0, 0, 0);                  \
    }                                                                         \
    __builtin_amdgcn_s_setprio(0);                                            \
    if (tap_ == TAPS - 1 && (T_) != TT - 1) {                                 \
        __syncthreads();                                                      \
        STAGEA((icv_ + 1) * 64);                                              \
        __syncthreads();                                                      \
    } else if ((T_) != TT - 1) {                                              \
        __syncthreads();                                                      \
    }                                                                         \
  } while (0)

template <int IN_W, int LOG_OW, int KH, int KW, int TH, int HTB, int NT, int MF,
          bool OCMAJOR>
__global__ __launch_bounds__(512, 1) void conv_bn_relu(
    const u16* __restrict__ A, const u16* __restrict__ Wb,
    const float* __restrict__ bias, const float* __restrict__ bnsc,
    const float* __restrict__ bnsh, void* __restrict__ outp) {
    constexpr int OW = 1 << LOG_OW;
    constexpr int NF = NT / 64;
    constexpr int AROWS = (TH + KH - 1) * IN_W;
    constexpr int NCALL = AROWS / 8;
    constexpr int WCALL = NT / 8;
    constexpr int TAPS = KH * KW;
    constexpr int TT = 8 * TAPS;
    constexpr int OUTH = TH * HTB;
    constexpr int NTILES = 512 / NT;
    __shared__ u16 As_l[AROWS * 64];
    __shared__ u16 Ws_l[2][NT * 64];

    const int tid = threadIdx.x;
    const int bid = blockIdx.x;
    const int n0 = (bid % NTILES) * NT;
    const int mt = bid / NTILES;
    const int b = mt / HTB;
    const int h0 = (mt % HTB) * TH;

    const int lane = tid & 63;
    const int wv = tid >> 6;
    const int wm = wv >> 2, wn = wv & 3;
    const int l15 = lane & 15, grp = lane >> 4;

    int rowb[MF];
    #pragma unroll
    for (int mf = 0; mf < MF; ++mf) {
        int pos = wm * MF * 16 + mf * 16 + l15;
        rowb[mf] = (pos >> LOG_OW) * IN_W + (pos & (OW - 1));
    }
    int ocr[NF];
    #pragma unroll
    for (int nf = 0; nf < NF; ++nf) ocr[nf] = wn * (NT / 4) + nf * 16 + l15;

    // shared per-lane pre-swizzled global offset (shorts); row stride 512 for
    // both A (position rows) and W (oc rows)
    const int aoff = (lane >> 3) * 512 + (((lane & 7) ^ ((lane >> 3) & 7)) * 8);

    const size_t abase = ((size_t)b * (OUTH + KH - 1) + h0) * IN_W * 512;
    const u16* gA = A + abase;

    f32x4 acc[MF][NF];
    #pragma unroll
    for (int i = 0; i < MF; ++i)
        #pragma unroll
        for (int j = 0; j < NF; ++j) acc[i][j] = f32x4{0.f, 0.f, 0.f, 0.f};

    // prologue: As(ic0=0) + Ws[0] <- W(tap0, ic0=0) via DMA
    STAGEA(0);
    STAGEW(0, 0);
    __syncthreads();   // drains gload_lds vmcnt for all waves

    #pragma unroll 1
    for (int T = 0; T < TT; T += 2) {
        BODY(T, 0);
        BODY(T + 1, 1);
    }

    // epilogue: y = relu(conv*sc + (bias*sc + sh))
    #pragma unroll
    for (int nf = 0; nf < NF; ++nf) {
        int oc = n0 + wn * (NT / 4) + nf * 16 + l15;
        float scv = bnsc[oc], shv = bnsh[oc], bi = bias[oc];
        float shh = fmaf(bi, scv, shv);
        #pragma unroll
        for (int mf = 0; mf < MF; ++mf) {
            #pragma unroll
            for (int r = 0; r < 4; ++r) {
                int pos = wm * MF * 16 + mf * 16 + grp * 4 + r;  // row=(lane>>4)*4+reg
                int lh = pos >> LOG_OW, lw = pos & (OW - 1);
                int h = h0 + lh;
                float v = fmaxf(fmaf(acc[mf][nf][r], scv, shh), 0.f);
                if (OCMAJOR) {
                    float* o = (float*)outp;
                    o[(((size_t)b * 512 + oc) * OUTH + h) * OW + lw] = v;
                } else {
                    u16* o = (u16*)outp;
                    o[(((size_t)b * OUTH + h) * OW + lw) * 512 + oc] = f2bf(v);
                }
            }
        }
    }
}

// ---------------- pools ----------------
// in: [8][1024][8][512] bf16 (relu'd, >=0) -> out: [8][516][4][512] bf16, pads zeroed
__global__ void pool1(const u16* __restrict__ in, u16* __restrict__ out) {
    int idx = blockIdx.x * 256 + threadIdx.x;
    if (idx >= 8 * 516 * 4 * 64) return;
    int icv = idx & 63, rest = idx >> 6;
    int w = rest & 3; rest >>= 2;
    int hp = rest % 516, b = rest / 516;
    u16* op = out + (((size_t)(b * 516 + hp) * 4 + w) * 512 + icv * 8);
    if (hp < 2 || hp >= 514) { *(int4*)op = int4{0, 0, 0, 0}; return; }
    int h = (hp - 2) * 2, wi = w * 2;
    const u16* p0 = in + (((size_t)(b * 1024 + h) * 8 + wi) * 512 + icv * 8);
    const u16* a = p0;
    const u16* bq = p0 + 512;
    const u16* c = p0 + 8 * 512;
    const u16* d = p0 + 8 * 512 + 512;
    u16 r[8];
    #pragma unroll
    for (int e = 0; e < 8; ++e) {
        u16 m1 = a[e] > bq[e] ? a[e] : bq[e];     // bf16 >=0: bit pattern monotone
        u16 m2 = c[e] > d[e] ? c[e] : d[e];
        r[e] = m1 > m2 ? m1 : m2;
    }
    *(int4*)op = *(const int4*)r;
}

// in: fp32 [8][512][512][2] (>=0) -> d_out fp32 [8][512][256]
__global__ void pool2(const float* __restrict__ in, float* __restrict__ out) {
    int idx = blockIdx.x * 256 + threadIdx.x;
    if (idx >= 8 * 512 * 256) return;
    const float* p = in + (size_t)idx * 4;
    out[idx] = fmaxf(fmaxf(p[0], p[1]), fmaxf(p[2], p[3]));
}

// ---------------- launch ----------------
extern "C" void kernel_launch(void* const* d_in, const int* in_sizes, int n_in,
                              void* d_out, int out_size, void* d_ws, size_t ws_size,
                              hipStream_t stream) {
    const float* x  = (const float*)d_in[0];
    const float* w1 = (const float*)d_in[1];
    const float* b1 = (const float*)d_in[2];
    const float* g1 = (const float*)d_in[3];
    const float* be1 = (const float*)d_in[4];
    const float* m1 = (const float*)d_in[5];
    const float* v1 = (const float*)d_in[6];
    const float* w2 = (const float*)d_in[7];
    const float* b2 = (const float*)d_in[8];
    const float* g2 = (const float*)d_in[9];
    const float* be2 = (const float*)d_in[10];
    const float* m2 = (const float*)d_in[11];
    const float* v2 = (const float*)d_in[12];
    float* out = (float*)d_out;

    char* ws = (char*)d_ws;
    u16* gathered  = (u16*)(ws);                   // 101,056,512 B
    u16* w1b       = (u16*)(ws + 101056512);       // 13,107,200 B
    u16* w2b       = (u16*)(ws + 114163712);       //  7,864,320 B
    float* bn1s    = (float*)(ws + 122028032);
    float* bn1t    = bn1s + 512;
    float* bn2s    = bn1s + 1024;
    float* bn2t    = bn1s + 1536;
    u16* conv1out  = (u16*)(ws + 122036224);       // 67,108,864 B
    u16* pooled1   = (u16*)(ws);                   // aliases gathered (dead by then)
    float* conv2out = (float*)(ws + 16908288);     // 16,777,216 B (inside gathered region)

    prep_w1<<<(25 * 512 * 512 + 255) / 256, 256, 0, stream>>>(w1, w1b);
    prep_w2<<<(15 * 512 * 512 + 255) / 256, 256, 0, stream>>>(w2, w2b);
    prep_bn<<<2, 256, 0, stream>>>(g1, be1, m1, v1, bn1s, bn1t);
    prep_bn<<<2, 256, 0, stream>>>(g2, be2, m2, v2, bn2s, bn2t);
    zero_gpads<<<(8 * 4 * 768 + 255) / 256, 256, 0, stream>>>(gathered);
    gather_topk<<<8192, 256, 0, stream>>>(x, gathered);

    // conv1: 256pos x 256oc tile, TH=32, grid 8*32*2 = 512
    conv_bn_relu<12, 3, 5, 5, 32, 32, 256, 8, false><<<512, 512, 0, stream>>>(
        gathered, w1b, b1, bn1s, bn1t, conv1out);
    pool1<<<(8 * 516 * 4 * 64 + 255) / 256, 256, 0, stream>>>(conv1out, pooled1);
    // conv2: 64pos x 256oc tile, TH=32, grid 8*16*2 = 256
    conv_bn_relu<4, 1, 5, 3, 32, 16, 256, 2, true><<<256, 512, 0, stream>>>(
        pooled1, w2b, b2, bn2s, bn2t, conv2out);
    pool2<<<(8 * 512 * 256 + 255) / 256, 256, 0, stream>>>(conv2out, out);
}

// Round 5
// 1027.978 us; speedup vs baseline: 1.4591x; 1.1478x over previous
//
#include <hip/hip_runtime.h>
#include <hip/hip_bf16.h>

typedef short bf16x8 __attribute__((ext_vector_type(8)));
typedef float f32x16 __attribute__((ext_vector_type(16)));
typedef unsigned short u16;

__device__ __forceinline__ u16 f2bf(float v) {
    union { __hip_bfloat16 h; u16 u; } cv;
    cv.h = __float2bfloat16(v);
    return cv.u;
}

__device__ __forceinline__ void gld_lds16(const u16* g, u16* l) {
    __builtin_amdgcn_global_load_lds(
        (const __attribute__((address_space(1))) void*)g,
        (__attribute__((address_space(3))) void*)l, 16, 0, 0);
}

// ---------------- prep kernels ----------------
__global__ void prep_w1(const float* __restrict__ w, u16* __restrict__ o) {
    int idx = blockIdx.x * 256 + threadIdx.x;
    if (idx >= 25 * 512 * 512) return;
    int ic = idx & 511, rest = idx >> 9;
    int oc = rest & 511, tap = rest >> 9;
    int kh = tap / 5, kw = tap % 5;
    float v = w[(((size_t)oc * 512 + ic) * 5 + kh) * 5 + kw];
    o[idx] = f2bf(v);
}

__global__ void prep_w2(const float* __restrict__ w, u16* __restrict__ o) {
    int idx = blockIdx.x * 256 + threadIdx.x;
    if (idx >= 15 * 512 * 512) return;
    int ic = idx & 511, rest = idx >> 9;
    int oc = rest & 511, tap = rest >> 9;
    int kh = tap / 3, kw = tap % 3;
    float v = w[(((size_t)oc * 512 + ic) * 5 + kh) * 3 + kw];
    o[idx] = f2bf(v);
}

__global__ void prep_bn(const float* __restrict__ g, const float* __restrict__ b,
                        const float* __restrict__ m, const float* __restrict__ v,
                        float* __restrict__ scale, float* __restrict__ shift) {
    int i = blockIdx.x * 256 + threadIdx.x;
    if (i >= 512) return;
    float s = g[i] * rsqrtf(v[i] + 1e-5f);
    scale[i] = s;
    shift[i] = b[i] - m[i] * s;
}

// zero the H-pad rows {0,1,1026,1027} of gathered [8][1028][12][512] bf16
__global__ void zero_gpads(u16* __restrict__ g) {
    int idx = blockIdx.x * 256 + threadIdx.x;   // int4 units
    if (idx >= 8 * 4 * 768) return;             // 768 int4 per (b,row)
    int part = idx % 768;
    int combo = idx / 768;
    int b = combo >> 2, r4 = combo & 3;
    int row = (r4 < 2) ? r4 : (1024 + r4);      // 0,1,1026,1027
    u16* p = g + ((size_t)(b * 1028 + row) * 12 * 512) + (size_t)part * 8;
    *(int4*)p = int4{0, 0, 0, 0};
}

// ---------------- scores + top-k + gather ----------------
__global__ __launch_bounds__(256) void gather_topk(const float* __restrict__ x,
                                                   u16* __restrict__ g) {
    int bt = blockIdx.x;
    int b = bt >> 10, t = bt & 1023;
    const float* xb = x + (size_t)b * 1024 * 512;
    const float* xt = xb + (size_t)t * 512;
    __shared__ float xts[512];
    __shared__ float sc[23];
    __shared__ int sel[12];
    int tid = threadIdx.x;
    for (int i = tid; i < 512; i += 256) xts[i] = xt[i];
    __syncthreads();
    int j0 = t - 11; if (j0 < 0) j0 = 0;
    int j1 = t + 11; if (j1 > 1023) j1 = 1023;
    int C = j1 - j0 + 1;                        // 12..23, always >= 12
    int wave = tid >> 6, lane = tid & 63;
    for (int c = wave; c < C; c += 4) {
        const float* xj = xb + (size_t)(j0 + c) * 512;
        double s = 0.0;
        #pragma unroll
        for (int e = 0; e < 8; ++e) {
            int d = lane * 8 + e;
            s += (double)xj[d] * (double)xts[d];
        }
        #pragma unroll
        for (int off = 32; off; off >>= 1) s += __shfl_xor(s, off, 64);
        if (lane == 0) sc[c] = (float)(s / 22.627416997969522);  // / sqrt(512)
    }
    __syncthreads();
    if (tid == 0) {
        int cnt = 0;
        for (int c = 0; c < C; ++c) {
            float v = sc[c];
            int r = 0;
            for (int k = 0; k < C; ++k) {
                float u = sc[k];
                r += (u > v) || (u == v && k < c);   // stable: lower index wins ties
            }
            if (r < 12) sel[cnt++] = j0 + c;         // ascending j == sorted ids
        }
    }
    __syncthreads();
    u16* dst = g + ((size_t)(b * 1028 + t + 2) * 12) * 512;
    for (int i = tid; i < 12 * 512; i += 256) {
        int s_ = i >> 9, d = i & 511;
        dst[i] = f2bf(xb[(size_t)sel[s_] * 512 + d]);
    }
}

// ---------------- implicit-GEMM conv + bias + BN + ReLU ----------------
// A: [b][outH+KH-1][IN_W][512] bf16 (H zero-padded). Wb: [tap][oc 512][ic 512].
// LDS (content-swizzled, 128B rows of 8 16B-chunks):
//   slot (row, s) holds global chunk s ^ (row&7); read chunk c at s = c^(row&7).
// As: single buffer, one ic-64 chunk, re-staged once per chunk (DMA).
// Ws: RING-3 (3 x 32KB), staged 2 taps ahead via global_load_lds.
// Per body: STAGEW(T+2) -> s_waitcnt vmcnt(8) (counted, never drains the
// in-flight W(T+1)/W(T+2)) -> s_barrier -> setprio+MFMA -> s_barrier.
// Chunk-start bodies use vmcnt(4) to additionally force the As DMA complete.
// MFMA: v_mfma_f32_32x32x16_bf16; wave tile (MF32*32) x 64; 8 waves 2m x 4n.

#define STAGEW(SLOT, TN) do {                                                 \
    int TNc_ = (TN) < TT ? (TN) : (TN) - TT;                                  \
    int icv_ = TNc_ / TAPS, tp_ = TNc_ - icv_ * TAPS;                         \
    const u16* wp_ = Wb + (size_t)tp_ * 262144 + (size_t)n0 * 512             \
                     + icv_ * 64;                                             \
    const u16* gw_ = wp_ + (size_t)(wv * 4) * 4096 + aoff;                    \
    u16* ldsw_ = &Ws_l[(SLOT)][wv * 4 * 512];                                 \
    _Pragma("unroll")                                                         \
    for (int i_ = 0; i_ < 4; ++i_)                                            \
        gld_lds16(gw_ + (size_t)i_ * 4096, ldsw_ + i_ * 512);                 \
  } while (0)

#define STAGEA(CH) do {                                                       \
    const u16* ga_ = gA + (CH) * 64;                                          \
    _Pragma("unroll 1")                                                       \
    for (int c_ = wv; c_ < NCALL; c_ += 8)                                    \
        gld_lds16(ga_ + (size_t)c_ * 4096 + aoff, &As_l[c_ * 512]);           \
  } while (0)

#define MFMA_PHASE(TOFF, SR) do {                                             \
    __builtin_amdgcn_s_setprio(1);                                            \
    _Pragma("unroll")                                                         \
    for (int k_ = 0; k_ < 4; ++k_) {                                          \
        bf16x8 afr[MF32], bfr[2];                                             \
        int cA_ = 2 * k_ + kgrp;                                              \
        _Pragma("unroll")                                                     \
        for (int mf = 0; mf < MF32; ++mf) {                                   \
            int row_ = rowb[mf] + (TOFF);                                     \
            afr[mf] = *(const bf16x8*)&As_l[row_ * 64 +                       \
                          ((cA_ ^ (row_ & 7)) << 3)];                         \
        }                                                                     \
        _Pragma("unroll")                                                     \
        for (int nf = 0; nf < 2; ++nf)                                        \
            bfr[nf] = *(const bf16x8*)&Ws_l[(SR)][ocr[nf] * 64 +              \
                          ((cA_ ^ (ocr[nf] & 7)) << 3)];                      \
        _Pragma("unroll")                                                     \
        for (int mf = 0; mf < MF32; ++mf)                                     \
            _Pragma("unroll")                                                 \
            for (int nf = 0; nf < 2; ++nf)                                    \
                acc[mf][nf] = __builtin_amdgcn_mfma_f32_32x32x16_bf16(        \
                    afr[mf], bfr[nf], acc[mf][nf], 0, 0, 0);                  \
    }                                                                         \
    __builtin_amdgcn_s_setprio(0);                                            \
  } while (0)

template <int IN_W, int LOG_OW, int KH, int KW, int TH, int HTB, int MF32,
          int CPX, bool OCMAJOR>
__global__ __launch_bounds__(512, 1) void conv_bn_relu(
    const u16* __restrict__ A, const u16* __restrict__ Wb,
    const float* __restrict__ bias, const float* __restrict__ bnsc,
    const float* __restrict__ bnsh, void* __restrict__ outp) {
    constexpr int OW = 1 << LOG_OW;
    constexpr int NT = 256;
    constexpr int AROWS = (TH + KH - 1) * IN_W;
    constexpr int NCALL = AROWS / 8;
    constexpr int TAPS = KH * KW;
    constexpr int TT = 8 * TAPS;
    constexpr int OUTH = TH * HTB;
    __shared__ u16 As_l[AROWS * 64];
    __shared__ u16 Ws_l[3][NT * 64];

    const int tid = threadIdx.x;
    const int bid = blockIdx.x;
    const int lb = (bid & 7) * CPX + (bid >> 3);   // XCD-chunked swizzle
    const int n0 = (lb & 1) * NT;
    const int mt = lb >> 1;
    const int b = mt / HTB;
    const int h0 = (mt % HTB) * TH;

    const int lane = tid & 63;
    const int wv = tid >> 6;
    const int wm = wv >> 2, wn = wv & 3;
    const int l31 = lane & 31, kgrp = lane >> 5;

    int rowb[MF32];
    #pragma unroll
    for (int mf = 0; mf < MF32; ++mf) {
        int pos = wm * MF32 * 32 + mf * 32 + l31;
        rowb[mf] = (pos >> LOG_OW) * IN_W + (pos & (OW - 1));
    }
    int ocr[2];
    #pragma unroll
    for (int nf = 0; nf < 2; ++nf) ocr[nf] = wn * 64 + nf * 32 + l31;

    // per-lane pre-swizzled global offset (shorts); row stride 512 shorts
    const int aoff = (lane >> 3) * 512 + (((lane & 7) ^ ((lane >> 3) & 7)) * 8);

    const size_t abase = ((size_t)b * (OUTH + KH - 1) + h0) * IN_W * 512;
    const u16* gA = A + abase;

    f32x16 acc[MF32][2];
    #pragma unroll
    for (int i = 0; i < MF32; ++i)
        #pragma unroll
        for (int j = 0; j < 2; ++j)
            acc[i][j] = f32x16{0.f,0.f,0.f,0.f,0.f,0.f,0.f,0.f,
                               0.f,0.f,0.f,0.f,0.f,0.f,0.f,0.f};

    // prologue: As(chunk 0) + W(0)->slot0, W(1)->slot1
    STAGEA(0);
    STAGEW(0, 0);
    STAGEW(1, 1);

    #pragma unroll 1
    for (int ch = 0; ch < 8; ++ch) {
        const int Tb = ch * TAPS;
        int sR = Tb % 3;
        int sW = (sR + 2) % 3;
        // ---- body t=0 (chunk start): force As + W(Tb) landed, keep 4 in flight
        STAGEW(sW, Tb + 2);
        asm volatile("s_waitcnt vmcnt(4)" ::: "memory");
        __builtin_amdgcn_s_barrier();
        __builtin_amdgcn_sched_barrier(0);
        MFMA_PHASE(0, sR);
        __builtin_amdgcn_sched_barrier(0);
        __builtin_amdgcn_s_barrier();
        sR = sR == 2 ? 0 : sR + 1;
        sW = sW == 2 ? 0 : sW + 1;
        // ---- bodies t=1..TAPS-1: keep 8 in flight (W(T+1), W(T+2))
        #pragma unroll 1
        for (int t = 1; t < TAPS; ++t) {
            STAGEW(sW, Tb + t + 2);
            asm volatile("s_waitcnt vmcnt(8)" ::: "memory");
            __builtin_amdgcn_s_barrier();
            __builtin_amdgcn_sched_barrier(0);
            int kh_ = t / KW;
            int toff_ = kh_ * IN_W + (t - kh_ * KW);
            MFMA_PHASE(toff_, sR);
            __builtin_amdgcn_sched_barrier(0);
            __builtin_amdgcn_s_barrier();
            sR = sR == 2 ? 0 : sR + 1;
            sW = sW == 2 ? 0 : sW + 1;
        }
        // after end-barrier: all reads of As(ch) done -> restage
        if (ch < 7) STAGEA(ch + 1);
    }
    asm volatile("s_waitcnt vmcnt(0)" ::: "memory");

    // epilogue: y = relu(conv*sc + (bias*sc + sh))
    // C/D 32x32: col = lane&31, row = (reg&3) + 8*(reg>>2) + 4*(lane>>5)
    #pragma unroll
    for (int nf = 0; nf < 2; ++nf) {
        int oc = n0 + wn * 64 + nf * 32 + l31;
        float scv = bnsc[oc], shv = bnsh[oc], bi = bias[oc];
        float shh = fmaf(bi, scv, shv);
        #pragma unroll
        for (int mf = 0; mf < MF32; ++mf) {
            #pragma unroll
            for (int r = 0; r < 16; ++r) {
                int m = (r & 3) + 8 * (r >> 2) + 4 * kgrp;
                int pos = wm * MF32 * 32 + mf * 32 + m;
                int lh = pos >> LOG_OW, lw = pos & (OW - 1);
                int h = h0 + lh;
                float v = fmaxf(fmaf(acc[mf][nf][r], scv, shh), 0.f);
                if (OCMAJOR) {
                    float* o = (float*)outp;
                    o[(((size_t)b * 512 + oc) * OUTH + h) * OW + lw] = v;
                } else {
                    u16* o = (u16*)outp;
                    o[(((size_t)b * OUTH + h) * OW + lw) * 512 + oc] = f2bf(v);
                }
            }
        }
    }
}

// ---------------- pools ----------------
// in: [8][1024][8][512] bf16 (relu'd, >=0) -> out: [8][516][4][512] bf16, pads zeroed
__global__ void pool1(const u16* __restrict__ in, u16* __restrict__ out) {
    int idx = blockIdx.x * 256 + threadIdx.x;
    if (idx >= 8 * 516 * 4 * 64) return;
    int icv = idx & 63, rest = idx >> 6;
    int w = rest & 3; rest >>= 2;
    int hp = rest % 516, b = rest / 516;
    u16* op = out + (((size_t)(b * 516 + hp) * 4 + w) * 512 + icv * 8);
    if (hp < 2 || hp >= 514) { *(int4*)op = int4{0, 0, 0, 0}; return; }
    int h = (hp - 2) * 2, wi = w * 2;
    const u16* p0 = in + (((size_t)(b * 1024 + h) * 8 + wi) * 512 + icv * 8);
    const u16* a = p0;
    const u16* bq = p0 + 512;
    const u16* c = p0 + 8 * 512;
    const u16* d = p0 + 8 * 512 + 512;
    u16 r[8];
    #pragma unroll
    for (int e = 0; e < 8; ++e) {
        u16 m1 = a[e] > bq[e] ? a[e] : bq[e];     // bf16 >=0: bit pattern monotone
        u16 m2 = c[e] > d[e] ? c[e] : d[e];
        r[e] = m1 > m2 ? m1 : m2;
    }
    *(int4*)op = *(const int4*)r;
}

// in: fp32 [8][512][512][2] (>=0) -> d_out fp32 [8][512][256]
__global__ void pool2(const float* __restrict__ in, float* __restrict__ out) {
    int idx = blockIdx.x * 256 + threadIdx.x;
    if (idx >= 8 * 512 * 256) return;
    const float* p = in + (size_t)idx * 4;
    out[idx] = fmaxf(fmaxf(p[0], p[1]), fmaxf(p[2], p[3]));
}

// ---------------- launch ----------------
extern "C" void kernel_launch(void* const* d_in, const int* in_sizes, int n_in,
                              void* d_out, int out_size, void* d_ws, size_t ws_size,
                              hipStream_t stream) {
    const float* x  = (const float*)d_in[0];
    const float* w1 = (const float*)d_in[1];
    const float* b1 = (const float*)d_in[2];
    const float* g1 = (const float*)d_in[3];
    const float* be1 = (const float*)d_in[4];
    const float* m1 = (const float*)d_in[5];
    const float* v1 = (const float*)d_in[6];
    const float* w2 = (const float*)d_in[7];
    const float* b2 = (const float*)d_in[8];
    const float* g2 = (const float*)d_in[9];
    const float* be2 = (const float*)d_in[10];
    const float* m2 = (const float*)d_in[11];
    const float* v2 = (const float*)d_in[12];
    float* out = (float*)d_out;

    char* ws = (char*)d_ws;
    u16* gathered  = (u16*)(ws);                   // 101,056,512 B
    u16* w1b       = (u16*)(ws + 101056512);       // 13,107,200 B
    u16* w2b       = (u16*)(ws + 114163712);       //  7,864,320 B
    float* bn1s    = (float*)(ws + 122028032);
    float* bn1t    = bn1s + 512;
    float* bn2s    = bn1s + 1024;
    float* bn2t    = bn1s + 1536;
    u16* conv1out  = (u16*)(ws + 122036224);       // 67,108,864 B
    u16* pooled1   = (u16*)(ws);                   // aliases gathered (dead by then)
    float* conv2out = (float*)(ws + 16908288);     // 16,777,216 B (inside gathered region)

    prep_w1<<<(25 * 512 * 512 + 255) / 256, 256, 0, stream>>>(w1, w1b);
    prep_w2<<<(15 * 512 * 512 + 255) / 256, 256, 0, stream>>>(w2, w2b);
    prep_bn<<<2, 256, 0, stream>>>(g1, be1, m1, v1, bn1s, bn1t);
    prep_bn<<<2, 256, 0, stream>>>(g2, be2, m2, v2, bn2s, bn2t);
    zero_gpads<<<(8 * 4 * 768 + 255) / 256, 256, 0, stream>>>(gathered);
    gather_topk<<<8192, 256, 0, stream>>>(x, gathered);

    // conv1: 256pos x 256oc tile, TH=32, MF32=4, grid 8*32*2 = 512, CPX=64
    conv_bn_relu<12, 3, 5, 5, 32, 32, 4, 64, false><<<512, 512, 0, stream>>>(
        gathered, w1b, b1, bn1s, bn1t, conv1out);
    pool1<<<(8 * 516 * 4 * 64 + 255) / 256, 256, 0, stream>>>(conv1out, pooled1);
    // conv2: 64pos x 256oc tile, TH=32, MF32=1, grid 8*16*2 = 256, CPX=32
    conv_bn_relu<4, 1, 5, 3, 32, 16, 1, 32, true><<<256, 512, 0, stream>>>(
        pooled1, w2b, b2, bn2s, bn2t, conv2out);
    pool2<<<(8 * 512 * 256 + 255) / 256, 256, 0, stream>>>(conv2out, out);
}